// Round 10
// baseline (570.954 us; speedup 1.0000x reference)
//
#include <hip/hip_runtime.h>
#include <math.h>

static constexpr int NNODES = 50000;
static constexpr int NEDGES = 600000;
static constexpr int D = 128;
static constexpr int NPART = (NNODES + 255) / 256;  // 196

typedef __attribute__((ext_vector_type(8))) short short8;   // 8 bf16 in 4 VGPRs
typedef __attribute__((ext_vector_type(4))) float f32x4;

static __device__ inline unsigned short f2bf_rne(float f) {
  unsigned u = __float_as_uint(f);
  unsigned r = (u + 0x7FFFu + ((u >> 16) & 1u)) >> 16;
  return (unsigned short)r;
}
static __device__ inline float bf2f(unsigned short s) {
  return __uint_as_float(((unsigned)s) << 16);
}
// order-preserving f32-bits -> u32 map (for u32 atomicMax on floats)
static __device__ inline unsigned map_ord(unsigned u) {
  return (u & 0x80000000u) ? ~u : (u | 0x80000000u);
}
static __device__ inline unsigned unmap_ord(unsigned m) {
  return (m & 0x80000000u) ? (m ^ 0x80000000u) : ~m;
}

// ---------------- x -> bf16 hi/lo split ----------------
__global__ __launch_bounds__(256) void split_kernel(const float* __restrict__ x,
    unsigned short* __restrict__ hi, unsigned short* __restrict__ lo, int n4) {
  int i = blockIdx.x * 256 + threadIdx.x;
  if (i >= n4) return;
  f32x4 v = *(const f32x4*)(x + (size_t)i * 4);
  ushort4 h, l;
  h.x = f2bf_rne(v[0]); l.x = f2bf_rne(v[0] - bf2f(h.x));
  h.y = f2bf_rne(v[1]); l.y = f2bf_rne(v[1] - bf2f(h.y));
  h.z = f2bf_rne(v[2]); l.z = f2bf_rne(v[2] - bf2f(h.z));
  h.w = f2bf_rne(v[3]); l.w = f2bf_rne(v[3] - bf2f(h.w));
  *(ushort4*)(hi + (size_t)i * 4) = h;
  *(ushort4*)(lo + (size_t)i * 4) = l;
}

// ---------------- CSR build ----------------

__global__ void count_kernel(const int* __restrict__ dst, int* __restrict__ cnt, int nE) {
  int i = blockIdx.x * blockDim.x + threadIdx.x;
  if (i < nE) atomicAdd(&cnt[dst[i]], 1);
}

__global__ void scan_partial(const int* __restrict__ cnt, int* __restrict__ part, int n) {
  int i = blockIdx.x * 256 + threadIdx.x;
  int v = (i < n) ? cnt[i] : 0;
#pragma unroll
  for (int off = 32; off > 0; off >>= 1) v += __shfl_down(v, off);
  __shared__ int ws[4];
  int wid = threadIdx.x >> 6, lane = threadIdx.x & 63;
  if (lane == 0) ws[wid] = v;
  __syncthreads();
  if (threadIdx.x == 0) part[blockIdx.x] = ws[0] + ws[1] + ws[2] + ws[3];
}

__global__ void scan_root(const int* __restrict__ part, int* __restrict__ pscan,
                          int* __restrict__ rs_last, int np) {
  int i = threadIdx.x;                 // single block, 256 threads, np <= 256
  int v = (i < np) ? part[i] : 0;
  int incl = v;
  int lane = i & 63, wid = i >> 6;
#pragma unroll
  for (int off = 1; off < 64; off <<= 1) {
    int t = __shfl_up(incl, off);
    if (lane >= off) incl += t;
  }
  __shared__ int ws[4];
  if (lane == 63) ws[wid] = incl;
  __syncthreads();
  int woff = 0;
  for (int w = 0; w < wid; ++w) woff += ws[w];
  if (i < np) pscan[i] = woff + incl - v;  // exclusive
  if (i == 0) *rs_last = ws[0] + ws[1] + ws[2] + ws[3];
}

__global__ void scan_apply(const int* __restrict__ cnt, const int* __restrict__ pscan,
                           int* __restrict__ rs, int* __restrict__ cursor, int n) {
  int i = blockIdx.x * 256 + threadIdx.x;
  int v = (i < n) ? cnt[i] : 0;
  int incl = v;
  int lane = threadIdx.x & 63, wid = threadIdx.x >> 6;
#pragma unroll
  for (int off = 1; off < 64; off <<= 1) {
    int t = __shfl_up(incl, off);
    if (lane >= off) incl += t;
  }
  __shared__ int ws[4];
  if (lane == 63) ws[wid] = incl;
  __syncthreads();
  int woff = pscan[blockIdx.x];
  for (int w = 0; w < wid; ++w) woff += ws[w];
  int ex = woff + incl - v;
  if (i < n) { rs[i] = ex; cursor[i] = ex; }
}

__global__ void fill_kernel(const int* __restrict__ src, const int* __restrict__ dst,
                            int* __restrict__ cursor, int* __restrict__ csr,
                            int* __restrict__ csr_row, int nE) {
  int i = blockIdx.x * blockDim.x + threadIdx.x;
  if (i < nE) {
    int d = dst[i];
    int p = atomicAdd(&cursor[d], 1);
    csr[p] = src[i];
    csr_row[p] = d;
  }
}

// ---------------- weight pre-pack into MFMA B-fragment layout ----------------
// B-fragment (16x16x32): lane l holds B[k = ks*32 + (l>>4)*8 + e][j = jb*16 + (l&15)]
// Packed flat index: ((jb*4 + ks)*64 + lane)*8 + e -> per-lane 16B coalesced loads.
struct PackArgs {
  const float* src[4];
  unsigned short* hi[4];
  unsigned short* lo[4];
};

__global__ void pack_all(PackArgs pa) {
  int mat = blockIdx.x >> 3;                       // 0..3
  int tid = (blockIdx.x & 7) * 256 + threadIdx.x;  // 0..2047
  const float* Wm = pa.src[mat];
  unsigned short* hi = pa.hi[mat];
  unsigned short* lo = pa.lo[mat];
  int jb = tid >> 8;
  int ks = (tid >> 6) & 3;
  int lane = tid & 63;
  int j = jb * 16 + (lane & 15);
  int k0 = ks * 32 + (lane >> 4) * 8;
#pragma unroll
  for (int e = 0; e < 8; ++e) {
    float v = Wm[(k0 + e) * D + j];
    unsigned short h = f2bf_rne(v);
    float rem = v - bf2f(h);
    unsigned short l = f2bf_rne(rem);
    hi[tid * 8 + e] = h;
    lo[tid * 8 + e] = l;
  }
}

// ---------------- fused layer: edge-parallel gather -> LDS -> dual MFMA ----------------
// Block = 64 rows, one contiguous CSR slice (~768 edges). Gather is EDGE-parallel:
// all 4 waves stripe the slice; per edge one coalesced 256B row load + 2 LDS
// atomicMax (order-preserving u32 map of f32) — no per-row dependent chains
// (rounds 7/8 showed row-serial gather is chain-latency-bound: occupancy 16->28%
// moved duration 0%). Then unmap/pack to the XOR-swizzled bf16 A-tile in place,
// and the round-8 MFMA K-loop.
// agg is exact bf16 (lo==0): agg@W = agg@Whi + agg@Wlo (2 MFMA).
// h = hhi+hlo:               h@R  = hhi@Rhi + hlo@Rhi + hhi@Rlo (3 MFMA).
__global__ __launch_bounds__(256) void layer_fused(
    const unsigned short* __restrict__ hhi, const unsigned short* __restrict__ hlo,
    const int* __restrict__ rs, const int* __restrict__ csr,
    const int* __restrict__ csr_row,
    const unsigned short* __restrict__ Whi, const unsigned short* __restrict__ Wlo,
    const unsigned short* __restrict__ Rhi, const unsigned short* __restrict__ Rlo,
    const float* __restrict__ bias, float* __restrict__ outf,
    unsigned short* __restrict__ ohi, unsigned short* __restrict__ olo, int nrows) {
  __shared__ unsigned tile[64 * 128];   // 32KB: [row][feat] mapped-u32, then bf16 A-tile in place
  const int tid = threadIdx.x;
  const int lane = tid & 63;
  const int wv = tid >> 6;
  const int m_lo = lane & 15;
  const int sub = lane >> 4;            // 0..3
  const int base = blockIdx.x * 64;
  const unsigned* __restrict__ xb = (const unsigned*)hhi;

  // ---- init tile to map(-inf) ----
  // 256 threads x 8 iters x uint4 = 8192 u32 exactly (round-9 bug: stride-8
  // pattern left half the tile uninitialized and wrote OOB -> absmax 1.9).
  {
    const unsigned MINF = 0x007FFFFFu;  // map_ord(bits(-inf))
    uint4 m4 = make_uint4(MINF, MINF, MINF, MINF);
#pragma unroll
    for (int i = 0; i < 8; ++i)
      *(uint4*)&tile[tid * 4 + i * 1024] = m4;
  }
  __syncthreads();

  // ---- edge-parallel gather ----
  const int erows = (base + 64 < nrows) ? base + 64 : nrows;
  const int eb = rs[base];
  const int ee = rs[erows];
  const int total = ee - eb;
  const int per = (total + 3) >> 2;
  int my_beg = eb + wv * per;
  int my_end = my_beg + per; if (my_end > ee) my_end = ee;
  for (int g = my_beg; g < my_end; g += 64) {
    const int navail = (my_end - g < 64) ? my_end - g : 64;
    int sv = 0, rv = 0;
    if (lane < navail) { sv = csr[g + lane]; rv = csr_row[g + lane] - base; }
    for (int e = 0; e < navail; ++e) {
      int s = __shfl(sv, e);
      int rr = __shfl(rv, e);
      unsigned v = xb[(size_t)s * 64 + lane];
      unsigned m0 = map_ord(v << 16);          // feat 2*lane
      unsigned m1 = map_ord(v & 0xFFFF0000u);  // feat 2*lane+1
      atomicMax(&tile[rr * 128 + 2 * lane], m0);
      atomicMax(&tile[rr * 128 + 2 * lane + 1], m1);
    }
  }
  __syncthreads();

  // ---- convert in place: unmap, zero isolated/tail rows, pack bf16 pairs, swizzle ----
  // thread t: row lr = t>>2, feat quarter fq = t&3 (feats fq*32 .. fq*32+31)
  {
    const int lr = tid >> 2, fq = tid & 3;
    unsigned mv[32];
#pragma unroll
    for (int f = 0; f < 32; ++f) mv[f] = tile[lr * 128 + fq * 32 + f];
    const int grow = base + lr;
    bool zero = true;
    if (grow < nrows) zero = (rs[grow] == rs[grow + 1]);  // isolated -> 0 (PyG fill)
    __syncthreads();
#pragma unroll
    for (int gq = 0; gq < 4; ++gq) {
      uint4 w;
      unsigned pk[4];
#pragma unroll
      for (int k = 0; k < 4; ++k) {
        unsigned uA = unmap_ord(mv[gq * 8 + 2 * k]);
        unsigned uB = unmap_ord(mv[gq * 8 + 2 * k + 1]);
        pk[k] = zero ? 0u : ((uA >> 16) | (uB & 0xFFFF0000u));
      }
      w.x = pk[0]; w.y = pk[1]; w.z = pk[2]; w.w = pk[3];
      // A-tile byte addr: lr*512 + ((fq*64 + gq*16) ^ ((lr&7)<<4))
      *(uint4*)((char*)tile + lr * 512 + ((fq * 64 + gq * 16) ^ ((lr & 7) << 4))) = w;
    }
  }
  __syncthreads();

  // ---- compute phase: K-loop, A from LDS (wave wv owns rows wv*16..wv*16+15) ----
  const int r_base = base + wv * 16;
  f32x4 acc[8];
#pragma unroll
  for (int jb = 0; jb < 8; ++jb) acc[jb] = (f32x4)0.f;

  float bv[8];
#pragma unroll
  for (int jb = 0; jb < 8; ++jb) bv[jb] = bias[jb * 16 + m_lo];

  const char* ldsc = (const char*)tile;
  const int ri = wv * 16 + m_lo;
  for (int ks = 0; ks < 4; ++ks) {
    short8 fa, fhh, fhl;
    {
      int bofs = ri * 512 + (((ks * 64) + (sub * 16)) ^ ((ri & 7) << 4));
      fa = *(const short8*)(ldsc + bofs);
      int row = r_base + m_lo; if (row >= nrows) row = nrows - 1;
      const size_t ro = (size_t)row * D + ks * 32 + sub * 8;
      fhh = *(const short8*)(hhi + ro);
      fhl = *(const short8*)(hlo + ro);
    }
#pragma unroll
    for (int jb = 0; jb < 8; ++jb) {
      const int pidx = ((jb * 4 + ks) * 64 + lane) * 8;
      short8 bwhi = *(const short8*)(Whi + pidx);
      short8 bwlo = *(const short8*)(Wlo + pidx);
      short8 brhi = *(const short8*)(Rhi + pidx);
      short8 brlo = *(const short8*)(Rlo + pidx);
      acc[jb] = __builtin_amdgcn_mfma_f32_16x16x32_bf16(fa,  bwhi, acc[jb], 0, 0, 0);
      acc[jb] = __builtin_amdgcn_mfma_f32_16x16x32_bf16(fa,  bwlo, acc[jb], 0, 0, 0);
      acc[jb] = __builtin_amdgcn_mfma_f32_16x16x32_bf16(fhh, brhi, acc[jb], 0, 0, 0);
      acc[jb] = __builtin_amdgcn_mfma_f32_16x16x32_bf16(fhl, brhi, acc[jb], 0, 0, 0);
      acc[jb] = __builtin_amdgcn_mfma_f32_16x16x32_bf16(fhh, brlo, acc[jb], 0, 0, 0);
    }
  }

  // D layout: col = lane&15, row-in-tile = sub*4 + reg
#pragma unroll
  for (int jb = 0; jb < 8; ++jb) {
#pragma unroll
    for (int r = 0; r < 4; ++r) {
      int row = r_base + sub * 4 + r;
      if (row < nrows) {
        float v = fmaxf(acc[jb][r] + bv[jb], 0.f);
        size_t o = (size_t)row * D + jb * 16 + m_lo;
        if (outf) {
          outf[o] = v;
        } else {
          unsigned short h = f2bf_rne(v);
          ohi[o] = h;
          olo[o] = f2bf_rne(v - bf2f(h));
        }
      }
    }
  }
}

// ---------------- launch ----------------

extern "C" void kernel_launch(void* const* d_in, const int* in_sizes, int n_in,
                              void* d_out, int out_size, void* d_ws, size_t ws_size,
                              hipStream_t stream) {
  const float* x  = (const float*)d_in[0];
  const int*   ei = (const int*)d_in[1];
  const float* W1 = (const float*)d_in[2];
  const float* b1 = (const float*)d_in[3];
  const float* R1 = (const float*)d_in[4];
  const float* W2 = (const float*)d_in[5];
  const float* b2 = (const float*)d_in[6];
  const float* R2 = (const float*)d_in[7];
  float* out = (float*)d_out;

  const int* src = ei;
  const int* dst = ei + NEDGES;

  char* ws = (char*)d_ws;
  size_t off = 0;
  auto alloc = [&](size_t bytes) -> void* {
    off = (off + 511) & ~(size_t)511;
    void* p = ws + off;
    off += bytes;
    return p;
  };
  const size_t NF = (size_t)NNODES * D;  // 6.4M elements
  unsigned short* xhi  = (unsigned short*)alloc(sizeof(short) * NF);
  unsigned short* xlo  = (unsigned short*)alloc(sizeof(short) * NF);
  unsigned short* hAhi = (unsigned short*)alloc(sizeof(short) * NF);
  unsigned short* hAlo = (unsigned short*)alloc(sizeof(short) * NF);
  unsigned short* hBhi = (unsigned short*)alloc(sizeof(short) * NF);
  unsigned short* hBlo = (unsigned short*)alloc(sizeof(short) * NF);
  int* cnt     = (int*)alloc(sizeof(int) * NNODES);
  int* rs      = (int*)alloc(sizeof(int) * (NNODES + 1));
  int* cursor  = (int*)alloc(sizeof(int) * NNODES);
  int* csr     = (int*)alloc(sizeof(int) * NEDGES);
  int* csr_row = (int*)alloc(sizeof(int) * NEDGES);
  int* part    = (int*)alloc(sizeof(int) * NPART);
  int* pscan   = (int*)alloc(sizeof(int) * NPART);
  const int PACKN = 2048 * 8;  // 16384 bf16 per matrix
  unsigned short* w1hi = (unsigned short*)alloc(sizeof(short) * PACKN);
  unsigned short* w1lo = (unsigned short*)alloc(sizeof(short) * PACKN);
  unsigned short* r1hi = (unsigned short*)alloc(sizeof(short) * PACKN);
  unsigned short* r1lo = (unsigned short*)alloc(sizeof(short) * PACKN);
  unsigned short* w2hi = (unsigned short*)alloc(sizeof(short) * PACKN);
  unsigned short* w2lo = (unsigned short*)alloc(sizeof(short) * PACKN);
  unsigned short* r2hi = (unsigned short*)alloc(sizeof(short) * PACKN);
  unsigned short* r2lo = (unsigned short*)alloc(sizeof(short) * PACKN);

  // x -> bf16 hi/lo (layer-1 operands)
  split_kernel<<<(int)(NF / 4 + 255) / 256, 256, 0, stream>>>(x, xhi, xlo, (int)(NF / 4));

  // weight pre-pack, all 4 matrices in one launch
  PackArgs pa;
  pa.src[0] = W1; pa.hi[0] = w1hi; pa.lo[0] = w1lo;
  pa.src[1] = R1; pa.hi[1] = r1hi; pa.lo[1] = r1lo;
  pa.src[2] = W2; pa.hi[2] = w2hi; pa.lo[2] = w2lo;
  pa.src[3] = R2; pa.hi[3] = r2hi; pa.lo[3] = r2lo;
  pack_all<<<32, 256, 0, stream>>>(pa);

  // CSR build (once per call; edge_index restored before every timed launch)
  hipMemsetAsync(cnt, 0, sizeof(int) * NNODES, stream);
  count_kernel<<<(NEDGES + 255) / 256, 256, 0, stream>>>(dst, cnt, NEDGES);
  scan_partial<<<NPART, 256, 0, stream>>>(cnt, part, NNODES);
  scan_root<<<1, 256, 0, stream>>>(part, pscan, &rs[NNODES], NPART);
  scan_apply<<<NPART, 256, 0, stream>>>(cnt, pscan, rs, cursor, NNODES);
  fill_kernel<<<(NEDGES + 255) / 256, 256, 0, stream>>>(src, dst, cursor, csr, csr_row, NEDGES);

  const int grid = (NNODES + 63) / 64;  // 782

  auto layer = [&](const unsigned short* hhi, const unsigned short* hlo,
                   const unsigned short* whi, const unsigned short* wlo,
                   const unsigned short* rhi, const unsigned short* rlo,
                   const float* b, float* outf, unsigned short* ohi, unsigned short* olo) {
    layer_fused<<<grid, 256, 0, stream>>>(hhi, hlo, rs, csr, csr_row, whi, wlo, rhi, rlo,
                                          b, outf, ohi, olo, NNODES);
  };

  layer(xhi,  xlo,  w1hi, w1lo, r1hi, r1lo, b1, nullptr, hAhi, hAlo);
  layer(hAhi, hAlo, w2hi, w2lo, r2hi, r2lo, b2, nullptr, hBhi, hBlo);
  layer(hBhi, hBlo, w2hi, w2lo, r2hi, r2lo, b2, nullptr, hAhi, hAlo);
  layer(hAhi, hAlo, w2hi, w2lo, r2hi, r2lo, b2, out, nullptr, nullptr);
}